// Round 5
// baseline (958.037 us; speedup 1.0000x reference)
//
#include <hip/hip_runtime.h>
#include <math.h>

#define Lnum 8
#define Bn 4
#define Tn 2048
#define Dn 256
#define Sn 512
#define BT (Bn*Tn)      // 8192
#define CHK 32
#define TC (Tn/CHK)     // 64

typedef __attribute__((ext_vector_type(8))) short bf16x8;
typedef __attribute__((ext_vector_type(4))) float f32x4;

__device__ __forceinline__ ushort f2bf(float f) {
    union { float f; unsigned u; } v; v.f = f;
    unsigned r = v.u + 0x7fffu + ((v.u >> 16) & 1u);   // RNE
    return (ushort)(r >> 16);
}
__device__ __forceinline__ float bf2f(ushort u) {
    union { unsigned u; float f; } v; v.u = ((unsigned)u) << 16; return v.f;
}

// direct global->LDS async copy, 16B per lane (dest = wave-uniform base + lane*16)
__device__ __forceinline__ void gload16(const void* g, void* l) {
    using u32 = unsigned int;
    auto gp = (const __attribute__((address_space(1))) u32*)(uintptr_t)g;
    auto lp = (__attribute__((address_space(3))) u32*)(uintptr_t)l;
    __builtin_amdgcn_global_load_lds(gp, lp, 16, 0, 0);
}

// ---------------- phase-preserving RMS norm: h[BT,D,2] -> xn[BT,512] bf16 ([xr|xi])
__global__ __launch_bounds__(256)
void norm_kernel(const float* __restrict__ h, const float* __restrict__ g,
                 ushort* __restrict__ xn)
{
    const int bt = blockIdx.x;
    const int d  = threadIdx.x;
    const float2 v = reinterpret_cast<const float2*>(h)[(size_t)bt*Dn + d];
    float sum = v.x*v.x + v.y*v.y;
    #pragma unroll
    for (int o = 32; o > 0; o >>= 1) sum += __shfl_down(sum, o);
    __shared__ float ws4[4];
    if ((threadIdx.x & 63) == 0) ws4[threadIdx.x >> 6] = sum;
    __syncthreads();
    const float tot = ws4[0] + ws4[1] + ws4[2] + ws4[3];
    const float rms = sqrtf(tot * (1.0f/Dn) + 1e-6f);
    const float scale = g[d] / rms;
    xn[(size_t)bt*512 + d]       = f2bf(v.x * scale);
    xn[(size_t)bt*512 + 256 + d] = f2bf(v.y * scale);
}

// ---------------- final norm, fp32 interleaved output
__global__ __launch_bounds__(256)
void out_norm_kernel(const float* __restrict__ h, const float* __restrict__ g,
                     float* __restrict__ out)
{
    const int bt = blockIdx.x;
    const int d  = threadIdx.x;
    const float2 v = reinterpret_cast<const float2*>(h)[(size_t)bt*Dn + d];
    float sum = v.x*v.x + v.y*v.y;
    #pragma unroll
    for (int o = 32; o > 0; o >>= 1) sum += __shfl_down(sum, o);
    __shared__ float ws4[4];
    if ((threadIdx.x & 63) == 0) ws4[threadIdx.x >> 6] = sum;
    __syncthreads();
    const float tot = ws4[0] + ws4[1] + ws4[2] + ws4[3];
    const float rms = sqrtf(tot * (1.0f/Dn) + 1e-6f);
    const float scale = g[d] / rms;
    float2 o; o.x = v.x * scale; o.y = v.y * scale;
    reinterpret_cast<float2*>(out)[(size_t)bt*Dn + d] = o;
}

// ======== GEMM1 (panel, barrier-free): zb[8192,2048]bf16 = xn[8192,512] @ W1^T
// Block: 64-col panel (B in LDS, 64KB, full K=512, pre-swizzled image), 256 rows.
// 8 waves x (32 rows x 64 cols). Grid 32 panels x 32 mgroups = 1024, XCD-colocated by mgroup.
__global__ __launch_bounds__(512, 4)
void gemm1_kernel(const ushort* __restrict__ A, const ushort* __restrict__ W1p,
                  ushort* __restrict__ Cb, const float* __restrict__ bias)
{
    __shared__ __align__(16) char lds[65536];
    const int tid = threadIdx.x, lane = tid & 63, wid = tid >> 6;
    const int lin = (blockIdx.x & 7)*128 + (blockIdx.x >> 3);
    const int mg = lin >> 5, panel = lin & 31;
    const int row0 = mg*256 + wid*32;
    const int col0 = panel*64;
    const int rl = lane & 15, kg = lane >> 4;

    // stage B panel image (linear copy; image is pre-XOR-swizzled by prep_w1)
    const char* src = (const char*)(W1p + (size_t)panel*32768);
    #pragma unroll
    for (int r = 0; r < 8; ++r)
        gload16(src + r*8192 + tid*16, lds + r*8192 + wid*1024);
    asm volatile("s_waitcnt vmcnt(0)" ::: "memory");
    __syncthreads();

    const ushort* pa = A + (size_t)(row0 + rl)*512 + kg*8;
    const int rb = rl*1024;          // per-lane LDS row base (bytes)
    const int z7 = rl & 7;           // swizzle key (col&7 == rl&7 since ni*16 % 8 == 0)

    f32x4 acc[2][4] = {};
    #pragma unroll
    for (int ks = 0; ks < 16; ++ks) {
        const bf16x8 a0 = *(const bf16x8*)(pa + ks*32);
        const bf16x8 a1 = *(const bf16x8*)(pa + 16*512 + ks*32);
        const int sw = (((ks*4 + kg) ^ z7) << 4);
        #pragma unroll
        for (int ni = 0; ni < 4; ++ni) {
            const bf16x8 b = *(const bf16x8*)(lds + ni*16384 + rb + sw);
            acc[0][ni] = __builtin_amdgcn_mfma_f32_16x16x32_bf16(a0, b, acc[0][ni], 0, 0, 0);
            acc[1][ni] = __builtin_amdgcn_mfma_f32_16x16x32_bf16(a1, b, acc[1][ni], 0, 0, 0);
        }
    }

    const int rbase = (lane >> 4)*4;
    #pragma unroll
    for (int mi = 0; mi < 2; ++mi) {
        #pragma unroll
        for (int ni = 0; ni < 4; ++ni) {
            const int gcol = col0 + ni*16 + rl;
            const float badd = bias[gcol];
            const bool sg = (gcol >= 1024) && (gcol < 1536);
            #pragma unroll
            for (int r = 0; r < 4; ++r) {
                const int grow = row0 + mi*16 + rbase + r;
                float v = acc[mi][ni][r] + badd;
                if (sg) v = 1.0f/(1.0f + __expf(-v));
                Cb[(size_t)grow*2048 + gcol] = f2bf(v);
            }
        }
    }
}

// ======== GEMM2 (panel, barrier-free): y = hsb[8192,1024] @ W2^T + dx(zb 1536+),
// fused residual into h. Block: 32-col panel (64KB LDS, full K=1024), 256 rows.
// 8 waves x (32 rows x 32 cols). Grid 16 panels x 32 mgroups = 512.
__global__ __launch_bounds__(512, 4)
void gemm2_kernel(const ushort* __restrict__ A, const ushort* __restrict__ W2p,
                  const ushort* __restrict__ zb, float* __restrict__ h)
{
    __shared__ __align__(16) char lds[65536];
    const int tid = threadIdx.x, lane = tid & 63, wid = tid >> 6;
    const int lin = (blockIdx.x & 7)*64 + (blockIdx.x >> 3);
    const int mg = lin >> 4, panel = lin & 15;
    const int row0 = mg*256 + wid*32;
    const int col0 = panel*32;
    const int rl = lane & 15, kg = lane >> 4;

    const char* src = (const char*)(W2p + (size_t)panel*32768);
    #pragma unroll
    for (int r = 0; r < 8; ++r)
        gload16(src + r*8192 + tid*16, lds + r*8192 + wid*1024);
    asm volatile("s_waitcnt vmcnt(0)" ::: "memory");
    __syncthreads();

    const ushort* pa = A + (size_t)(row0 + rl)*1024 + kg*8;
    const int rb = rl*2048;
    const int z7 = rl & 7;

    f32x4 acc[2][2] = {};
    #pragma unroll
    for (int ks = 0; ks < 32; ++ks) {
        const bf16x8 a0 = *(const bf16x8*)(pa + ks*32);
        const bf16x8 a1 = *(const bf16x8*)(pa + 16*1024 + ks*32);
        const int sw = (((ks*4 + kg) ^ z7) << 4);
        #pragma unroll
        for (int ni = 0; ni < 2; ++ni) {
            const bf16x8 b = *(const bf16x8*)(lds + ni*32768 + rb + sw);
            acc[0][ni] = __builtin_amdgcn_mfma_f32_16x16x32_bf16(a0, b, acc[0][ni], 0, 0, 0);
            acc[1][ni] = __builtin_amdgcn_mfma_f32_16x16x32_bf16(a1, b, acc[1][ni], 0, 0, 0);
        }
    }

    const int rbase = (lane >> 4)*4;
    #pragma unroll
    for (int mi = 0; mi < 2; ++mi) {
        #pragma unroll
        for (int ni = 0; ni < 2; ++ni) {
            const int gcol = col0 + ni*16 + rl;   // parity(gcol)==parity(lane)
            #pragma unroll
            for (int r = 0; r < 4; ++r) {
                const int grow = row0 + mi*16 + rbase + r;
                float v = acc[mi][ni][r] + bf2f(zb[(size_t)grow*2048 + 1536 + gcol]);
                const float p = __shfl_xor(v, 1);
                const float yr = (gcol & 1) ? p : v;
                h[(size_t)grow*512 + gcol] += 0.1f*(yr*v + v);
            }
        }
    }
}

// ---------------- scan pass 1: per-chunk (P, h_end) with h_start=0 (read-only over zb)
__global__ __launch_bounds__(256)
void scan_part1(const ushort* __restrict__ zb, const float* __restrict__ theta,
                const float* __restrict__ dp, float4* __restrict__ PH)
{
    const int c = blockIdx.x, b = blockIdx.y;
    const int s = blockIdx.z*256 + threadIdx.x;
    const float th = theta[s], ct = cosf(th), st = sinf(th);
    const float damp = 0.5f + 0.5f/(1.0f + __expf(-dp[s]));
    float hr = 0.f, hi = 0.f, Pr = 1.f, Pi = 0.f;
    const ushort* row = zb + (size_t)(b*Tn + c*TC)*2048;
    for (int t = 0; t < TC; ++t, row += 2048) {
        const float br = bf2f(row[s]), bi = bf2f(row[512+s]), g = bf2f(row[1024+s]);
        const float mm = (1.0f - g)*damp;
        const float mc = mm*ct, ms = mm*st;
        const float rr = mc*hr - ms*hi, ri = ms*hr + mc*hi;
        hr = g*br + rr;  hi = g*bi + ri;
        const float pr = mc*Pr - ms*Pi, pi = ms*Pr + mc*Pi;
        Pr = pr; Pi = pi;
    }
    PH[((size_t)c*Bn + b)*Sn + s] = make_float4(Pr, Pi, hr, hi);
}

// ---------------- scan pass 2: sequential combine across chunks (tiny)
__global__ __launch_bounds__(256)
void scan_combine(const float4* __restrict__ PH, const float* __restrict__ h0,
                  float2* __restrict__ cin)
{
    const int idx = blockIdx.x*256 + threadIdx.x;   // b*S + s
    const int b = idx / Sn, s = idx % Sn;
    float cr = h0[(size_t)idx*2], ci = h0[(size_t)idx*2 + 1];
    for (int c = 0; c < CHK; ++c) {
        const size_t o = ((size_t)c*Bn + b)*Sn + s;
        cin[o] = make_float2(cr, ci);
        const float4 ph = PH[o];
        const float nr = ph.z + ph.x*cr - ph.y*ci;
        const float ni = ph.w + ph.y*cr + ph.x*ci;
        cr = nr; ci = ni;
    }
}

// ---------------- scan pass 3: exact scan with carry-in, write bf16 [hs_r|hs_i]
__global__ __launch_bounds__(256)
void scan_apply(const ushort* __restrict__ zb, const float* __restrict__ theta,
                const float* __restrict__ dp, const float2* __restrict__ cin,
                ushort* __restrict__ hsb)
{
    const int c = blockIdx.x, b = blockIdx.y;
    const int s = blockIdx.z*256 + threadIdx.x;
    const float th = theta[s], ct = cosf(th), st = sinf(th);
    const float damp = 0.5f + 0.5f/(1.0f + __expf(-dp[s]));
    const float2 c0 = cin[((size_t)c*Bn + b)*Sn + s];
    float hr = c0.x, hi = c0.y;
    const ushort* row = zb + (size_t)(b*Tn + c*TC)*2048;
    ushort* hrow = hsb + (size_t)(b*Tn + c*TC)*1024;
    for (int t = 0; t < TC; ++t, row += 2048, hrow += 1024) {
        const float br = bf2f(row[s]), bi = bf2f(row[512+s]), g = bf2f(row[1024+s]);
        const float mm = (1.0f - g)*damp;
        const float mc = mm*ct, ms = mm*st;
        const float rr = mc*hr - ms*hi, ri = ms*hr + mc*hi;
        hr = g*br + rr;  hi = g*bi + ri;
        hrow[s]       = f2bf(hr);
        hrow[512 + s] = f2bf(hi);
    }
}

// ---------------- weight prep: W1 panel images (pre-XOR-swizzled LDS layout)
// image element: panel p, col c (0..63), granule g2 (0..63), ko (0..7)
//   stores W1_logical[n = p*64+c][k = (g2 ^ (c&7))*8 + ko]
__global__ __launch_bounds__(256)
void prep_w1(const float* __restrict__ Bwr, const float* __restrict__ Bwi,
             const float* __restrict__ Dwr, const float* __restrict__ Dwi,
             const float* __restrict__ Gw, ushort* __restrict__ W1p)
{
    const int l = blockIdx.y;
    const int idx = blockIdx.x*256 + threadIdx.x;   // [0, 1048576)
    const int panel = idx >> 15;
    const int col = (idx >> 9) & 63;
    const int r = idx & 511;
    const int k = (((r >> 3) ^ (col & 7)) << 3) | (r & 7);
    const int n = (panel << 6) | col;
    const float* bwr = Bwr + (size_t)l*Dn*Sn;
    const float* bwi = Bwi + (size_t)l*Dn*Sn;
    const float* dwr = Dwr + (size_t)l*Dn*Dn;
    const float* dwi = Dwi + (size_t)l*Dn*Dn;
    const float* gw  = Gw  + (size_t)l*2*Dn*Sn;
    float v;
    if (n < 512)        { const int s = n;      v = (k < 256) ? bwr[k*Sn + s] : -bwi[(k-256)*Sn + s]; }
    else if (n < 1024)  { const int s = n-512;  v = (k < 256) ? bwi[k*Sn + s] :  bwr[(k-256)*Sn + s]; }
    else if (n < 1536)  { const int s = n-1024; v = gw[(size_t)k*Sn + s]; }
    else {
        const int j = n - 1536, d = j >> 1;
        if ((j & 1) == 0) v = (k < 256) ? dwr[k*Dn + d] : -dwi[(k-256)*Dn + d];
        else              v = (k < 256) ? dwi[k*Dn + d] :  dwr[(k-256)*Dn + d];
    }
    W1p[(size_t)l*2048*512 + idx] = f2bf(v);
}

// ---------------- weight prep: W2 panel images (pre-XOR-swizzled), cols interleaved (yr,yi)
__global__ __launch_bounds__(256)
void prep_w2(const float* __restrict__ Cwr, const float* __restrict__ Cwi,
             ushort* __restrict__ W2p)
{
    const int l = blockIdx.y;
    const int idx = blockIdx.x*256 + threadIdx.x;   // [0, 524288)
    const int panel = idx >> 15;
    const int col = (idx >> 10) & 31;
    const int r = idx & 1023;
    const int k = (((r >> 3) ^ (col & 7)) << 3) | (r & 7);
    const int n = (panel << 5) | col;
    const float* cwr = Cwr + (size_t)l*Sn*Dn;
    const float* cwi = Cwi + (size_t)l*Sn*Dn;
    const int d = n >> 1;
    float v;
    if ((n & 1) == 0) v = (k < 512) ? cwr[k*Dn + d] : -cwi[(k-512)*Dn + d];
    else              v = (k < 512) ? cwi[k*Dn + d] :  cwr[(k-512)*Dn + d];
    W2p[(size_t)l*512*1024 + idx] = f2bf(v);
}

// ---------------- bias prep
__global__ __launch_bounds__(256)
void prep_bias(const float* __restrict__ gb, float* __restrict__ biasf)
{
    const int l = blockIdx.y;
    const int n = blockIdx.x*256 + threadIdx.x;
    biasf[(size_t)l*2048 + n] = (n >= 1024 && n < 1536) ? gb[(size_t)l*Sn + n - 1024] : 0.0f;
}

extern "C" void kernel_launch(void* const* d_in, const int* in_sizes, int n_in,
                              void* d_out, int out_size, void* d_ws, size_t ws_size,
                              hipStream_t stream)
{
    const float* x      = (const float*)d_in[0];
    const float* h0     = (const float*)d_in[1];
    const float* theta  = (const float*)d_in[2];
    const float* dp     = (const float*)d_in[3];
    const float* B_wr   = (const float*)d_in[4];
    const float* B_wi   = (const float*)d_in[5];
    const float* C_wr   = (const float*)d_in[6];
    const float* C_wi   = (const float*)d_in[7];
    const float* D_wr   = (const float*)d_in[8];
    const float* D_wi   = (const float*)d_in[9];
    const float* gate_w = (const float*)d_in[10];
    const float* gate_b = (const float*)d_in[11];
    const float* norm_g = (const float*)d_in[12];
    const float* out_g  = (const float*)d_in[13];
    float* out = (float*)d_out;

    char* w = (char*)d_ws;
    float*  h     = (float*)w;   w += (size_t)BT*512*4;        // 16 MB
    float*  biasf = (float*)w;   w += (size_t)8*2048*4;        // 64 KB
    float4* PH    = (float4*)w;  w += (size_t)CHK*Bn*Sn*16;    // 1 MB
    float2* cin   = (float2*)w;  w += (size_t)CHK*Bn*Sn*8;     // 0.5 MB
    ushort* zb    = (ushort*)w;  w += (size_t)BT*2048*2;       // 32 MB
    ushort* xn    = (ushort*)w;  w += (size_t)BT*512*2;        // 8 MB
    ushort* hsb   = (ushort*)w;  w += (size_t)BT*1024*2;       // 16 MB
    ushort* W1p   = (ushort*)w;  w += (size_t)Lnum*2048*512*2; // 16 MB
    ushort* W2p   = (ushort*)w;  w += (size_t)Lnum*512*1024*2; // 8 MB

    hipMemcpyAsync(h, x, sizeof(float)*(size_t)BT*Dn*2, hipMemcpyDeviceToDevice, stream);

    prep_w1<<<dim3(2048*512/256, Lnum), 256, 0, stream>>>(B_wr, B_wi, D_wr, D_wi, gate_w, W1p);
    prep_w2<<<dim3(512*1024/256, Lnum), 256, 0, stream>>>(C_wr, C_wi, W2p);
    prep_bias<<<dim3(8, Lnum), 256, 0, stream>>>(gate_b, biasf);

    const dim3 gs(CHK, Bn, Sn/256);

    for (int l = 0; l < Lnum; ++l) {
        norm_kernel<<<BT, 256, 0, stream>>>(h, norm_g + (size_t)l*Dn, xn);

        gemm1_kernel<<<1024, 512, 0, stream>>>(xn, W1p + (size_t)l*2048*512, zb,
                                               biasf + (size_t)l*2048);

        scan_part1<<<gs, 256, 0, stream>>>(zb, theta + (size_t)l*Sn, dp + (size_t)l*Sn, PH);
        scan_combine<<<(Bn*Sn)/256, 256, 0, stream>>>(PH, h0 + (size_t)l*Bn*Sn*2, cin);
        scan_apply<<<gs, 256, 0, stream>>>(zb, theta + (size_t)l*Sn, dp + (size_t)l*Sn, cin, hsb);

        gemm2_kernel<<<512, 512, 0, stream>>>(hsb, W2p + (size_t)l*512*1024, zb, h);
    }

    out_norm_kernel<<<BT, 256, 0, stream>>>(h, out_g, out);
}

// Round 6
// 949.439 us; speedup vs baseline: 1.0091x; 1.0091x over previous
//
#include <hip/hip_runtime.h>
#include <math.h>

#define Lnum 8
#define Bn 4
#define Tn 2048
#define Dn 256
#define Sn 512
#define BT (Bn*Tn)      // 8192
#define CHK 64
#define TC (Tn/CHK)     // 32
#define ZW 1536         // zb row width: [bx_r|bx_i|gate]

typedef __attribute__((ext_vector_type(8))) short bf16x8;
typedef __attribute__((ext_vector_type(4))) float f32x4;

__device__ __forceinline__ ushort f2bf(float f) {
    union { float f; unsigned u; } v; v.f = f;
    unsigned r = v.u + 0x7fffu + ((v.u >> 16) & 1u);   // RNE
    return (ushort)(r >> 16);
}
__device__ __forceinline__ float bf2f(ushort u) {
    union { unsigned u; float f; } v; v.u = ((unsigned)u) << 16; return v.f;
}

// direct global->LDS async copy, 16B/lane (dest = wave-uniform base + lane*16)
__device__ __forceinline__ void gload16(const void* g, void* l) {
    using u32 = unsigned int;
    auto gp = (const __attribute__((address_space(1))) u32*)(uintptr_t)g;
    auto lp = (__attribute__((address_space(3))) u32*)(uintptr_t)l;
    __builtin_amdgcn_global_load_lds(gp, lp, 16, 0, 0);
}

// ---------------- phase-preserving RMS norm: h[BT,D,2] -> xn[BT,512] bf16 ([xr|xi])
__global__ __launch_bounds__(256)
void norm_kernel(const float* __restrict__ h, const float* __restrict__ g,
                 ushort* __restrict__ xn)
{
    const int bt = blockIdx.x;
    const int d  = threadIdx.x;
    const float2 v = reinterpret_cast<const float2*>(h)[(size_t)bt*Dn + d];
    float sum = v.x*v.x + v.y*v.y;
    #pragma unroll
    for (int o = 32; o > 0; o >>= 1) sum += __shfl_down(sum, o);
    __shared__ float ws4[4];
    if ((threadIdx.x & 63) == 0) ws4[threadIdx.x >> 6] = sum;
    __syncthreads();
    const float tot = ws4[0] + ws4[1] + ws4[2] + ws4[3];
    const float rms = sqrtf(tot * (1.0f/Dn) + 1e-6f);
    const float scale = g[d] / rms;
    xn[(size_t)bt*512 + d]       = f2bf(v.x * scale);
    xn[(size_t)bt*512 + 256 + d] = f2bf(v.y * scale);
}

// ---------------- final norm, fp32 interleaved output
__global__ __launch_bounds__(256)
void out_norm_kernel(const float* __restrict__ h, const float* __restrict__ g,
                     float* __restrict__ out)
{
    const int bt = blockIdx.x;
    const int d  = threadIdx.x;
    const float2 v = reinterpret_cast<const float2*>(h)[(size_t)bt*Dn + d];
    float sum = v.x*v.x + v.y*v.y;
    #pragma unroll
    for (int o = 32; o > 0; o >>= 1) sum += __shfl_down(sum, o);
    __shared__ float ws4[4];
    if ((threadIdx.x & 63) == 0) ws4[threadIdx.x >> 6] = sum;
    __syncthreads();
    const float tot = ws4[0] + ws4[1] + ws4[2] + ws4[3];
    const float rms = sqrtf(tot * (1.0f/Dn) + 1e-6f);
    const float scale = g[d] / rms;
    float2 o; o.x = v.x * scale; o.y = v.y * scale;
    reinterpret_cast<float2*>(out)[(size_t)bt*Dn + d] = o;
}

// ======== GEMM1 (A-stationary, barrier-free): zb[8192,1536]bf16 = xn @ W1^T
// Block: 64 rows (A in LDS, full K=512, XOR-swizzled) x 768 cols (ch half).
// 8 waves: wave w = 64 rows x 96 cols. B streamed from L2 (W half L2-resident/XCD).
// Grid 256 = 1 block/CU. bias+sigmoid on cols [1024,1536).
__global__ __launch_bounds__(512, 2)
void gemm1_kernel(const ushort* __restrict__ A, const ushort* __restrict__ W,
                  ushort* __restrict__ Cb, const float* __restrict__ bias)
{
    __shared__ __align__(16) char lds[65536];
    const int tid = threadIdx.x, lane = tid & 63, wid = tid >> 6;
    const int mg = blockIdx.x >> 1, ch = blockIdx.x & 1;   // XCD parity == ch parity
    const int row0 = mg * 64;
    const int wc0 = ch*768 + wid*96;
    const int rl = lane & 15, kg = lane >> 4, z7 = rl & 7;

    // stage A rows once: LDS[row][g] = A[row][g ^ (row&7)] via pre-swizzled source
    #pragma unroll
    for (int r = 0; r < 8; ++r) {
        const int row = r*8 + wid;
        gload16(A + (size_t)(row0 + row)*512 + ((lane ^ (row & 7))*8),
                lds + row*1024);
    }
    asm volatile("s_waitcnt vmcnt(0)" ::: "memory");
    __syncthreads();

    f32x4 acc[4][6] = {};
    const ushort* pb = W + (size_t)(wc0 + rl)*512 + kg*8;
    #pragma unroll
    for (int ks = 0; ks < 16; ++ks) {
        bf16x8 aF[4], bF[6];
        #pragma unroll
        for (int m = 0; m < 4; ++m)
            aF[m] = *(const bf16x8*)(lds + (m*16 + rl)*1024 + (((ks*4 + kg) ^ z7) << 4));
        #pragma unroll
        for (int n = 0; n < 6; ++n)
            bF[n] = *(const bf16x8*)(pb + (size_t)n*8192 + ks*32);
        #pragma unroll
        for (int n = 0; n < 6; ++n)
            #pragma unroll
            for (int m = 0; m < 4; ++m)
                acc[m][n] = __builtin_amdgcn_mfma_f32_16x16x32_bf16(aF[m], bF[n], acc[m][n], 0, 0, 0);
    }

    const int rbase = kg*4;
    #pragma unroll
    for (int m = 0; m < 4; ++m) {
        #pragma unroll
        for (int n = 0; n < 6; ++n) {
            const int gcol = wc0 + n*16 + rl;
            const float badd = bias[gcol];
            const bool sg = (gcol >= 1024);
            #pragma unroll
            for (int r = 0; r < 4; ++r) {
                const int grow = row0 + m*16 + rbase + r;
                float v = acc[m][n][r] + badd;
                if (sg) v = 1.0f/(1.0f + __expf(-v));
                Cb[(size_t)grow*ZW + gcol] = f2bf(v);
            }
        }
    }
}

// ======== GEMM2 (A-stationary, barrier-free): y = [hsb|xn] @ W2^T (K=1536),
// interleaved (yr,yi) cols, fused residual h += 0.1*((1+yr)*y).
// Block: 64 rows (hsb K-part in LDS 128KB swizzled; xn K-tail streamed) x 256 cols.
// 8 waves: 64 rows x 32 cols. Grid 256 = 1 block/CU.
__global__ __launch_bounds__(512, 2)
void gemm2_kernel(const ushort* __restrict__ hsb, const ushort* __restrict__ xn,
                  const ushort* __restrict__ W, float* __restrict__ h)
{
    __shared__ __align__(16) char lds[131072];
    const int tid = threadIdx.x, lane = tid & 63, wid = tid >> 6;
    const int mg = blockIdx.x >> 1, ch = blockIdx.x & 1;
    const int row0 = mg * 64;
    const int wc0 = ch*256 + wid*32;
    const int rl = lane & 15, kg = lane >> 4, z7 = rl & 7;

    // stage hsb rows (2KB each): LDS[row][g] = hsb[row][g ^ (row&7)]
    #pragma unroll
    for (int r = 0; r < 16; ++r) {
        const int lin = r*8 + wid;
        const int row = lin >> 1, half = lin & 1;
        gload16(hsb + (size_t)(row0 + row)*1024 + half*512 + ((lane ^ (row & 7))*8),
                lds + lin*1024);
    }
    asm volatile("s_waitcnt vmcnt(0)" ::: "memory");
    __syncthreads();

    f32x4 acc[4][2] = {};
    const ushort* pb = W + (size_t)(wc0 + rl)*1536 + kg*8;
    const ushort* px = xn + (size_t)(row0 + rl)*512 + kg*8;
    #pragma unroll
    for (int ks = 0; ks < 48; ++ks) {
        bf16x8 aF[4], bF[2];
        if (ks < 32) {
            #pragma unroll
            for (int m = 0; m < 4; ++m)
                aF[m] = *(const bf16x8*)(lds + (m*16 + rl)*2048 + (((ks*4 + kg) ^ z7) << 4));
        } else {
            #pragma unroll
            for (int m = 0; m < 4; ++m)
                aF[m] = *(const bf16x8*)(px + (size_t)m*16*512 + (ks - 32)*32);
        }
        #pragma unroll
        for (int n = 0; n < 2; ++n)
            bF[n] = *(const bf16x8*)(pb + (size_t)n*24576 + ks*32);
        #pragma unroll
        for (int n = 0; n < 2; ++n)
            #pragma unroll
            for (int m = 0; m < 4; ++m)
                acc[m][n] = __builtin_amdgcn_mfma_f32_16x16x32_bf16(aF[m], bF[n], acc[m][n], 0, 0, 0);
    }

    const int rbase = kg*4;
    #pragma unroll
    for (int m = 0; m < 4; ++m) {
        #pragma unroll
        for (int n = 0; n < 2; ++n) {
            const int gcol = wc0 + n*16 + rl;   // parity(gcol)==parity(lane)
            #pragma unroll
            for (int r = 0; r < 4; ++r) {
                const int grow = row0 + m*16 + rbase + r;
                float v = acc[m][n][r];
                const float p = __shfl_xor(v, 1);
                const float yr = (gcol & 1) ? p : v;
                h[(size_t)grow*512 + gcol] += 0.1f*(yr*v + v);
            }
        }
    }
}

// ---------------- scan pass 1: per-chunk (P, h_end) with h_start=0 (read-only over zb)
__global__ __launch_bounds__(256)
void scan_part1(const ushort* __restrict__ zb, const float* __restrict__ theta,
                const float* __restrict__ dp, float4* __restrict__ PH)
{
    const int c = blockIdx.x, b = blockIdx.y;
    const int s = blockIdx.z*256 + threadIdx.x;
    const float th = theta[s], ct = cosf(th), st = sinf(th);
    const float damp = 0.5f + 0.5f/(1.0f + __expf(-dp[s]));
    float hr = 0.f, hi = 0.f, Pr = 1.f, Pi = 0.f;
    const ushort* row = zb + (size_t)(b*Tn + c*TC)*ZW;
    for (int t = 0; t < TC; ++t, row += ZW) {
        const float br = bf2f(row[s]), bi = bf2f(row[512+s]), g = bf2f(row[1024+s]);
        const float mm = (1.0f - g)*damp;
        const float mc = mm*ct, ms = mm*st;
        const float rr = mc*hr - ms*hi, ri = ms*hr + mc*hi;
        hr = g*br + rr;  hi = g*bi + ri;
        const float pr = mc*Pr - ms*Pi, pi = ms*Pr + mc*Pi;
        Pr = pr; Pi = pi;
    }
    PH[((size_t)c*Bn + b)*Sn + s] = make_float4(Pr, Pi, hr, hi);
}

// ---------------- scan pass 2: sequential combine across chunks
__global__ __launch_bounds__(256)
void scan_combine(const float4* __restrict__ PH, const float* __restrict__ h0,
                  float2* __restrict__ cin)
{
    const int idx = blockIdx.x*256 + threadIdx.x;   // b*S + s
    const int b = idx / Sn, s = idx % Sn;
    float cr = h0[(size_t)idx*2], ci = h0[(size_t)idx*2 + 1];
    #pragma unroll 4
    for (int c = 0; c < CHK; ++c) {
        const size_t o = ((size_t)c*Bn + b)*Sn + s;
        cin[o] = make_float2(cr, ci);
        const float4 ph = PH[o];
        const float nr = ph.z + ph.x*cr - ph.y*ci;
        const float ni = ph.w + ph.y*cr + ph.x*ci;
        cr = nr; ci = ni;
    }
}

// ---------------- scan pass 3: exact scan with carry-in, write bf16 [hs_r|hs_i]
__global__ __launch_bounds__(256)
void scan_apply(const ushort* __restrict__ zb, const float* __restrict__ theta,
                const float* __restrict__ dp, const float2* __restrict__ cin,
                ushort* __restrict__ hsb)
{
    const int c = blockIdx.x, b = blockIdx.y;
    const int s = blockIdx.z*256 + threadIdx.x;
    const float th = theta[s], ct = cosf(th), st = sinf(th);
    const float damp = 0.5f + 0.5f/(1.0f + __expf(-dp[s]));
    const float2 c0 = cin[((size_t)c*Bn + b)*Sn + s];
    float hr = c0.x, hi = c0.y;
    const ushort* row = zb + (size_t)(b*Tn + c*TC)*ZW;
    ushort* hrow = hsb + (size_t)(b*Tn + c*TC)*1024;
    for (int t = 0; t < TC; ++t, row += ZW, hrow += 1024) {
        const float br = bf2f(row[s]), bi = bf2f(row[512+s]), g = bf2f(row[1024+s]);
        const float mm = (1.0f - g)*damp;
        const float mc = mm*ct, ms = mm*st;
        const float rr = mc*hr - ms*hi, ri = ms*hr + mc*hi;
        hr = g*br + rr;  hi = g*bi + ri;
        hrow[s]       = f2bf(hr);
        hrow[512 + s] = f2bf(hi);
    }
}

// ---------------- weight prep: W1n[1536][512] bf16 (N-major): [bx_r|bx_i|gate]
__global__ __launch_bounds__(256)
void prep_w1(const float* __restrict__ Bwr, const float* __restrict__ Bwi,
             const float* __restrict__ Gw, ushort* __restrict__ W1n)
{
    const int l = blockIdx.y, n = blockIdx.x;
    const float* bwr = Bwr + (size_t)l*Dn*Sn;
    const float* bwi = Bwi + (size_t)l*Dn*Sn;
    const float* gw  = Gw  + (size_t)l*2*Dn*Sn;
    #pragma unroll
    for (int j = 0; j < 2; ++j) {
        const int k = j*256 + threadIdx.x;
        float v;
        if (n < 512)        { const int s = n;      v = (k < 256) ? bwr[k*Sn + s] : -bwi[(k-256)*Sn + s]; }
        else if (n < 1024)  { const int s = n-512;  v = (k < 256) ? bwi[k*Sn + s] :  bwr[(k-256)*Sn + s]; }
        else                { const int s = n-1024; v = gw[(size_t)k*Sn + s]; }
        W1n[(size_t)l*1536*512 + (size_t)n*512 + k] = f2bf(v);
    }
}

// ---------------- weight prep: W2n[512][1536] bf16, K = [hs_r|hs_i|xr|xi],
// output cols interleaved (yr,yi)
__global__ __launch_bounds__(256)
void prep_w2(const float* __restrict__ Cwr, const float* __restrict__ Cwi,
             const float* __restrict__ Dwr, const float* __restrict__ Dwi,
             ushort* __restrict__ W2n)
{
    const int l = blockIdx.y, n = blockIdx.x;
    const float* cwr = Cwr + (size_t)l*Sn*Dn;
    const float* cwi = Cwi + (size_t)l*Sn*Dn;
    const float* dwr = Dwr + (size_t)l*Dn*Dn;
    const float* dwi = Dwi + (size_t)l*Dn*Dn;
    const int d = n >> 1;
    const bool im = (n & 1);
    #pragma unroll
    for (int j = 0; j < 6; ++j) {
        const int k = j*256 + threadIdx.x;
        float v;
        if (k < 512)       v = im ? cwi[k*Dn + d]          : cwr[k*Dn + d];
        else if (k < 1024) v = im ? cwr[(k-512)*Dn + d]    : -cwi[(k-512)*Dn + d];
        else if (k < 1280) v = im ? dwi[(k-1024)*Dn + d]   : dwr[(k-1024)*Dn + d];
        else               v = im ? dwr[(k-1280)*Dn + d]   : -dwi[(k-1280)*Dn + d];
        W2n[(size_t)l*512*1536 + (size_t)n*1536 + k] = f2bf(v);
    }
}

// ---------------- bias prep (1536 wide; gate bias in [1024,1536))
__global__ __launch_bounds__(256)
void prep_bias(const float* __restrict__ gb, float* __restrict__ biasf)
{
    const int l = blockIdx.y;
    const int n = blockIdx.x*256 + threadIdx.x;
    biasf[(size_t)l*1536 + n] = (n >= 1024) ? gb[(size_t)l*Sn + n - 1024] : 0.0f;
}

extern "C" void kernel_launch(void* const* d_in, const int* in_sizes, int n_in,
                              void* d_out, int out_size, void* d_ws, size_t ws_size,
                              hipStream_t stream)
{
    const float* x      = (const float*)d_in[0];
    const float* h0     = (const float*)d_in[1];
    const float* theta  = (const float*)d_in[2];
    const float* dp     = (const float*)d_in[3];
    const float* B_wr   = (const float*)d_in[4];
    const float* B_wi   = (const float*)d_in[5];
    const float* C_wr   = (const float*)d_in[6];
    const float* C_wi   = (const float*)d_in[7];
    const float* D_wr   = (const float*)d_in[8];
    const float* D_wi   = (const float*)d_in[9];
    const float* gate_w = (const float*)d_in[10];
    const float* gate_b = (const float*)d_in[11];
    const float* norm_g = (const float*)d_in[12];
    const float* out_g  = (const float*)d_in[13];
    float* out = (float*)d_out;

    char* w = (char*)d_ws;
    float*  h     = (float*)w;   w += (size_t)BT*512*4;         // 16 MB
    float*  biasf = (float*)w;   w += (size_t)8*1536*4;         // 48 KB
    float4* PH    = (float4*)w;  w += (size_t)CHK*Bn*Sn*16;     // 2 MB
    float2* cin   = (float2*)w;  w += (size_t)CHK*Bn*Sn*8;      // 1 MB
    ushort* zb    = (ushort*)w;  w += (size_t)BT*ZW*2;          // 24 MB
    ushort* xn    = (ushort*)w;  w += (size_t)BT*512*2;         // 8 MB
    ushort* hsb   = (ushort*)w;  w += (size_t)BT*1024*2;        // 16 MB
    ushort* W1n   = (ushort*)w;  w += (size_t)Lnum*1536*512*2;  // 12 MB
    ushort* W2n   = (ushort*)w;  w += (size_t)Lnum*512*1536*2;  // 12 MB

    hipMemcpyAsync(h, x, sizeof(float)*(size_t)BT*Dn*2, hipMemcpyDeviceToDevice, stream);

    prep_w1<<<dim3(1536, Lnum), 256, 0, stream>>>(B_wr, B_wi, gate_w, W1n);
    prep_w2<<<dim3(512, Lnum), 256, 0, stream>>>(C_wr, C_wi, D_wr, D_wi, W2n);
    prep_bias<<<dim3(6, Lnum), 256, 0, stream>>>(gate_b, biasf);

    const dim3 gs(CHK, Bn, Sn/256);

    for (int l = 0; l < Lnum; ++l) {
        norm_kernel<<<BT, 256, 0, stream>>>(h, norm_g + (size_t)l*Dn, xn);

        gemm1_kernel<<<256, 512, 0, stream>>>(xn, W1n + (size_t)l*1536*512, zb,
                                              biasf + (size_t)l*1536);

        scan_part1<<<gs, 256, 0, stream>>>(zb, theta + (size_t)l*Sn, dp + (size_t)l*Sn, PH);
        scan_combine<<<(Bn*Sn)/256, 256, 0, stream>>>(PH, h0 + (size_t)l*Bn*Sn*2, cin);
        scan_apply<<<gs, 256, 0, stream>>>(zb, theta + (size_t)l*Sn, dp + (size_t)l*Sn, cin, hsb);

        gemm2_kernel<<<256, 512, 0, stream>>>(hsb, xn, W2n + (size_t)l*512*1536, h);
    }

    out_norm_kernel<<<BT, 256, 0, stream>>>(h, out_g, out);
}

// Round 7
// 784.537 us; speedup vs baseline: 1.2211x; 1.2102x over previous
//
#include <hip/hip_runtime.h>
#include <math.h>

#define Lnum 8
#define Bn 4
#define Tn 2048
#define Dn 256
#define Sn 512
#define BT (Bn*Tn)      // 8192
#define ZW 1536         // zb row: [bx_r(512) | bx_i(512) | gate(512)]
#define WARM 48         // scan warmup; carry bound 0.7625^48 = 2.2e-6

typedef __attribute__((ext_vector_type(8))) short bf16x8;
typedef __attribute__((ext_vector_type(4))) float f32x4;

__device__ __forceinline__ ushort f2bf(float f) {
    union { float f; unsigned u; } v; v.f = f;
    unsigned r = v.u + 0x7fffu + ((v.u >> 16) & 1u);   // RNE
    return (ushort)(r >> 16);
}
__device__ __forceinline__ float bf2f(ushort u) {
    union { unsigned u; float f; } v; v.u = ((unsigned)u) << 16; return v.f;
}

// ---------------- phase-preserving RMS norm: h[BT,D,2] -> xnp (fragment-packed bf16)
// packed layout: xnp[((rowgrp*16 + ks)*64 + lane)*8 + e] = xn[rowgrp*16 + (lane&15)][ks*32 + (lane>>4)*8 + e]
__global__ __launch_bounds__(256)
void norm_kernel(const float* __restrict__ h, const float* __restrict__ g,
                 ushort* __restrict__ xnp)
{
    const int bt = blockIdx.x;
    const int d  = threadIdx.x;
    const float2 v = reinterpret_cast<const float2*>(h)[(size_t)bt*Dn + d];
    float sum = v.x*v.x + v.y*v.y;
    #pragma unroll
    for (int o = 32; o > 0; o >>= 1) sum += __shfl_down(sum, o);
    __shared__ float ws4[4];
    if ((threadIdx.x & 63) == 0) ws4[threadIdx.x >> 6] = sum;
    __syncthreads();
    const float tot = ws4[0] + ws4[1] + ws4[2] + ws4[3];
    const float rms = sqrtf(tot * (1.0f/Dn) + 1e-6f);
    const float scale = g[d] / rms;
    const int rowgrp = bt >> 4, rl = bt & 15;
    const int k1 = d, k2 = 256 + d;
    const size_t i1 = (((size_t)rowgrp*16 + (k1>>5))*64 + ((k1>>3)&3)*16 + rl)*8 + (k1&7);
    const size_t i2 = (((size_t)rowgrp*16 + (k2>>5))*64 + ((k2>>3)&3)*16 + rl)*8 + (k2&7);
    xnp[i1] = f2bf(v.x * scale);
    xnp[i2] = f2bf(v.y * scale);
}

// ---------------- final norm, fp32 interleaved output
__global__ __launch_bounds__(256)
void out_norm_kernel(const float* __restrict__ h, const float* __restrict__ g,
                     float* __restrict__ out)
{
    const int bt = blockIdx.x;
    const int d  = threadIdx.x;
    const float2 v = reinterpret_cast<const float2*>(h)[(size_t)bt*Dn + d];
    float sum = v.x*v.x + v.y*v.y;
    #pragma unroll
    for (int o = 32; o > 0; o >>= 1) sum += __shfl_down(sum, o);
    __shared__ float ws4[4];
    if ((threadIdx.x & 63) == 0) ws4[threadIdx.x >> 6] = sum;
    __syncthreads();
    const float tot = ws4[0] + ws4[1] + ws4[2] + ws4[3];
    const float rms = sqrtf(tot * (1.0f/Dn) + 1e-6f);
    const float scale = g[d] / rms;
    float2 o; o.x = v.x * scale; o.y = v.y * scale;
    reinterpret_cast<float2*>(out)[(size_t)bt*Dn + d] = o;
}

// ======== GEMM1 (no LDS, no barriers): zb[8192,1536]bf16 = xn @ W1^T
// All operands fragment-packed, every load = 1KB dense per wave.
// Block 8 waves, wave = 32 rows x 64 cols. Grid 768 (mg 256 x cg 3), XCD-chunked.
__global__ __launch_bounds__(512, 4)
void gemm1_kernel(const ushort* __restrict__ xnp, const ushort* __restrict__ W1f,
                  ushort* __restrict__ zb, const float* __restrict__ bias)
{
    const int tid = threadIdx.x, lane = tid & 63, wid = tid >> 6;
    const int lin = (blockIdx.x & 7)*96 + (blockIdx.x >> 3);   // XCD-contiguous
    const int mg = lin / 3, cg = lin % 3;                      // 32 rows, 512 cols
    const ushort* pa = xnp + ((size_t)mg*2*16*64)*8 + lane*8;
    const ushort* pb = W1f + ((size_t)(cg*32 + wid*4)*16*64)*8 + lane*8;

    f32x4 acc[2][4] = {};
    #pragma unroll
    for (int ks = 0; ks < 16; ++ks) {
        bf16x8 aF[2], bF[4];
        #pragma unroll
        for (int m = 0; m < 2; ++m)
            aF[m] = *(const bf16x8*)(pa + (size_t)(m*16 + ks)*512);
        #pragma unroll
        for (int n = 0; n < 4; ++n)
            bF[n] = *(const bf16x8*)(pb + (size_t)(n*16 + ks)*512);
        #pragma unroll
        for (int n = 0; n < 4; ++n)
            #pragma unroll
            for (int m = 0; m < 2; ++m)
                acc[m][n] = __builtin_amdgcn_mfma_f32_16x16x32_bf16(aF[m], bF[n], acc[m][n], 0, 0, 0);
    }

    const int rl = lane & 15, rbase = (lane >> 4)*4;
    #pragma unroll
    for (int m = 0; m < 2; ++m) {
        #pragma unroll
        for (int n = 0; n < 4; ++n) {
            const int gcol = cg*512 + wid*64 + n*16 + rl;
            const float badd = bias[gcol];
            const bool sg = (gcol >= 1024);
            #pragma unroll
            for (int r = 0; r < 4; ++r) {
                const int grow = mg*32 + m*16 + rbase + r;
                float v = acc[m][n][r] + badd;
                if (sg) v = 1.0f/(1.0f + __expf(-v));
                zb[(size_t)grow*ZW + gcol] = f2bf(v);
            }
        }
    }
}

// ======== fused scan + GEMM2 + residual.
// Block = one (b, 32-t chunk): phase1 local scan (warmup 48) writes hs into LDS
// in fragment layout; phase2 GEMM 32 rows x 512 cols, K=1536 (hs LDS + xn tail),
// fused h += 0.1*((1+yr)*y). Grid 256, 512 threads.
__global__ __launch_bounds__(512, 2)
void sg2_kernel(const ushort* __restrict__ zb, const ushort* __restrict__ xnp,
                const ushort* __restrict__ W2f, const float* __restrict__ theta,
                const float* __restrict__ dp, const float* __restrict__ h0,
                float* __restrict__ h)
{
    __shared__ ushort lds16[2*32*64*8];   // 64KB: [rowgrp(2)][ks(32)][lane(64)][e(8)]
    const int tid = threadIdx.x, lane = tid & 63, wid = tid >> 6;
    const int lin = (blockIdx.x & 7)*32 + (blockIdx.x >> 3);
    const int b = lin >> 6, c = lin & 63;
    const int t0 = c*32;

    // ---- phase 1: local scan, one s-channel per thread
    {
        const int s = tid;
        const float th = theta[s], ct = cosf(th), st = sinf(th);
        const float damp = 0.5f + 0.5f/(1.0f + __expf(-dp[s]));
        const int wstart = (t0 >= WARM) ? (t0 - WARM) : 0;
        float hr = 0.f, hi = 0.f;
        if (wstart == 0) {
            hr = h0[((size_t)b*Sn + s)*2];
            hi = h0[((size_t)b*Sn + s)*2 + 1];
        }
        const ushort* row = zb + (size_t)(b*Tn + wstart)*ZW;
        const int ks_r = (s >> 5)*512, ks_i = (16 + (s >> 5))*512;  // ushort offsets
        const int kgoff = ((s >> 3) & 3)*16;
        const int e = s & 7;
        for (int t = wstart; t < t0 + 32; ++t, row += ZW) {
            const float br = bf2f(row[s]), bi = bf2f(row[512+s]), g = bf2f(row[1024+s]);
            const float mm = (1.0f - g)*damp;
            const float mc = mm*ct, ms = mm*st;
            const float rr = mc*hr - ms*hi, ri = ms*hr + mc*hi;
            hr = g*br + rr;  hi = g*bi + ri;
            const int lt = t - t0;
            if (lt >= 0) {
                const int base = (lt >> 4)*32*512 + (kgoff + (lt & 15))*8 + e;
                lds16[base + ks_r] = f2bf(hr);
                lds16[base + ks_i] = f2bf(hi);
            }
        }
    }
    __syncthreads();

    // ---- phase 2: GEMM (wave = 32 rows x 64 cols)
    f32x4 acc[2][4] = {};
    const int rowgrp_g = (b*Tn + t0) >> 4;
    const ushort* pb = W2f + ((size_t)(wid*4)*48*64)*8 + lane*8;
    const ushort* px = xnp + ((size_t)rowgrp_g*16*64)*8 + lane*8;
    #pragma unroll
    for (int ks = 0; ks < 48; ++ks) {
        bf16x8 aF[2], bF[4];
        if (ks < 32) {
            aF[0] = *(const bf16x8*)(lds16 + (0*32 + ks)*512 + lane*8);
            aF[1] = *(const bf16x8*)(lds16 + (32 + ks)*512 + lane*8);
        } else {
            aF[0] = *(const bf16x8*)(px + (size_t)(0*16 + ks - 32)*512);
            aF[1] = *(const bf16x8*)(px + (size_t)(16 + ks - 32)*512);
        }
        #pragma unroll
        for (int n = 0; n < 4; ++n)
            bF[n] = *(const bf16x8*)(pb + (size_t)(n*48 + ks)*512);
        #pragma unroll
        for (int n = 0; n < 4; ++n)
            #pragma unroll
            for (int m = 0; m < 2; ++m)
                acc[m][n] = __builtin_amdgcn_mfma_f32_16x16x32_bf16(aF[m], bF[n], acc[m][n], 0, 0, 0);
    }

    const int rl = lane & 15, rbase = (lane >> 4)*4;
    #pragma unroll
    for (int m = 0; m < 2; ++m) {
        #pragma unroll
        for (int n = 0; n < 4; ++n) {
            const int gcol = wid*64 + n*16 + rl;   // parity(gcol) == parity(lane)
            #pragma unroll
            for (int r = 0; r < 4; ++r) {
                const int grow = b*Tn + t0 + m*16 + rbase + r;
                float v = acc[m][n][r];
                const float p = __shfl_xor(v, 1);
                const float yr = (gcol & 1) ? p : v;
                h[(size_t)grow*512 + gcol] += 0.1f*(yr*v + v);
            }
        }
    }
}

// ---------------- weight prep: W1f fragment-packed [colgrp(96)][ks(16)][lane][8]
// value = W1[n = colgrp*16 + (lane&15)][k = ks*32 + (lane>>4)*8 + e]
__global__ __launch_bounds__(512)
void prep_w1(const float* __restrict__ Bwr, const float* __restrict__ Bwi,
             const float* __restrict__ Gw, ushort* __restrict__ W1f)
{
    const int l = blockIdx.y;
    const int bx = blockIdx.x;          // colgrp*16 + ks
    const int lane = threadIdx.x >> 3, e = threadIdx.x & 7;
    const int n = (bx >> 4)*16 + (lane & 15);
    const int k = (bx & 15)*32 + (lane >> 4)*8 + e;
    const float* bwr = Bwr + (size_t)l*Dn*Sn;
    const float* bwi = Bwi + (size_t)l*Dn*Sn;
    const float* gw  = Gw  + (size_t)l*2*Dn*Sn;
    float v;
    if (n < 512)        { const int s = n;      v = (k < 256) ? bwr[k*Sn + s] : -bwi[(k-256)*Sn + s]; }
    else if (n < 1024)  { const int s = n-512;  v = (k < 256) ? bwi[k*Sn + s] :  bwr[(k-256)*Sn + s]; }
    else                { const int s = n-1024; v = gw[(size_t)k*Sn + s]; }
    W1f[(size_t)l*1536*512 + (size_t)bx*512 + threadIdx.x] = f2bf(v);
}

// ---------------- weight prep: W2f fragment-packed [colgrp(32)][ks(48)][lane][8]
// K = [hs_r(512) | hs_i(512) | xr,xi(512)]; cols interleaved (yr,yi)
__global__ __launch_bounds__(512)
void prep_w2(const float* __restrict__ Cwr, const float* __restrict__ Cwi,
             const float* __restrict__ Dwr, const float* __restrict__ Dwi,
             ushort* __restrict__ W2f)
{
    const int l = blockIdx.y;
    const int bx = blockIdx.x;          // colgrp*48 + ks
    const int lane = threadIdx.x >> 3, e = threadIdx.x & 7;
    const int n = (bx / 48)*16 + (lane & 15);
    const int k = (bx % 48)*32 + (lane >> 4)*8 + e;
    const float* cwr = Cwr + (size_t)l*Sn*Dn;
    const float* cwi = Cwi + (size_t)l*Sn*Dn;
    const float* dwr = Dwr + (size_t)l*Dn*Dn;
    const float* dwi = Dwi + (size_t)l*Dn*Dn;
    const int d = n >> 1;
    const bool im = (n & 1);
    float v;
    if (k < 512)       v = im ? cwi[k*Dn + d]        :  cwr[k*Dn + d];
    else if (k < 1024) v = im ? cwr[(k-512)*Dn + d]  : -cwi[(k-512)*Dn + d];
    else if (k < 1280) v = im ? dwi[(k-1024)*Dn + d] :  dwr[(k-1024)*Dn + d];
    else               v = im ? dwr[(k-1280)*Dn + d] : -dwi[(k-1280)*Dn + d];
    W2f[(size_t)l*512*1536 + (size_t)bx*512 + threadIdx.x] = f2bf(v);
}

// ---------------- bias prep (1536 wide; gate bias in [1024,1536))
__global__ __launch_bounds__(256)
void prep_bias(const float* __restrict__ gb, float* __restrict__ biasf)
{
    const int l = blockIdx.y;
    const int n = blockIdx.x*256 + threadIdx.x;
    biasf[(size_t)l*1536 + n] = (n >= 1024) ? gb[(size_t)l*Sn + n - 1024] : 0.0f;
}

extern "C" void kernel_launch(void* const* d_in, const int* in_sizes, int n_in,
                              void* d_out, int out_size, void* d_ws, size_t ws_size,
                              hipStream_t stream)
{
    const float* x      = (const float*)d_in[0];
    const float* h0     = (const float*)d_in[1];
    const float* theta  = (const float*)d_in[2];
    const float* dp     = (const float*)d_in[3];
    const float* B_wr   = (const float*)d_in[4];
    const float* B_wi   = (const float*)d_in[5];
    const float* C_wr   = (const float*)d_in[6];
    const float* C_wi   = (const float*)d_in[7];
    const float* D_wr   = (const float*)d_in[8];
    const float* D_wi   = (const float*)d_in[9];
    const float* gate_w = (const float*)d_in[10];
    const float* gate_b = (const float*)d_in[11];
    const float* norm_g = (const float*)d_in[12];
    const float* out_g  = (const float*)d_in[13];
    float* out = (float*)d_out;

    char* w = (char*)d_ws;
    float*  h     = (float*)w;   w += (size_t)BT*512*4;         // 16 MB
    float*  biasf = (float*)w;   w += (size_t)8*1536*4;         // 48 KB
    ushort* zb    = (ushort*)w;  w += (size_t)BT*ZW*2;          // 24 MB
    ushort* xnp   = (ushort*)w;  w += (size_t)BT*512*2;         // 8 MB
    ushort* W1f   = (ushort*)w;  w += (size_t)Lnum*1536*512*2;  // 12 MB
    ushort* W2f   = (ushort*)w;  w += (size_t)Lnum*512*1536*2;  // 12 MB

    hipMemcpyAsync(h, x, sizeof(float)*(size_t)BT*Dn*2, hipMemcpyDeviceToDevice, stream);

    prep_w1<<<dim3(1536, Lnum), 512, 0, stream>>>(B_wr, B_wi, gate_w, W1f);
    prep_w2<<<dim3(1536, Lnum), 512, 0, stream>>>(C_wr, C_wi, D_wr, D_wi, W2f);
    prep_bias<<<dim3(6, Lnum), 256, 0, stream>>>(gate_b, biasf);

    for (int l = 0; l < Lnum; ++l) {
        norm_kernel<<<BT, 256, 0, stream>>>(h, norm_g + (size_t)l*Dn, xnp);

        gemm1_kernel<<<768, 512, 0, stream>>>(xnp, W1f + (size_t)l*1536*512, zb,
                                              biasf + (size_t)l*1536);

        sg2_kernel<<<256, 512, 0, stream>>>(zb, xnp, W2f + (size_t)l*512*1536,
                                            theta + (size_t)l*Sn, dp + (size_t)l*Sn,
                                            h0 + (size_t)l*Bn*Sn*2, h);
    }

    out_norm_kernel<<<BT, 256, 0, stream>>>(h, out_g, out);
}